// Round 8
// baseline (12270.917 us; speedup 1.0000x reference)
//
#include <hip/hip_runtime.h>

// FPS: 2 batches x 131072 pts, 4096 samples/batch, seed = point 0.
// R8: SPECULATIVE XCD-LOCAL (L2) SYNC with TIMEOUT-DOWNGRADE.
// Liveness depends on NOTHING about placement/timing:
//  - workers by blockIdx only: bid%8==0 -> batch0 rank bid>>3, %8==1 ->
//    batch1; GRID=256 <= #CUs so residency is trivial; others exit.
//  - step 1 at system scope (R3-proven protocol). Slots carry XCC_ID
//    (hwreg 20, numeric form) + XOR check. All 32 blocks of a batch read
//    the SAME 32 slots -> identical verdict -> uniform upgrade to sc0
//    (same-XCD L2) iff ids uniform. No cross-batch peek, no barriers,
//    no claims (the R4/R5/R6 hang causes).
//  - EVERY poll bounded (KTO iters). Timeout => sticky downgrade to
//    system scope + re-store my whole 4-deep ring (held in registers) at
//    system scope. Any stuck configuration (garbage hwreg, mixed scopes,
//    spurious timeout) storms down to all-SYS with all live ring entries
//    republished at SYS == exactly R3, proven live. Worst case: R3 perf
//    plus a few ms one-time; no hang possible.
// Protocol per step (R3): fused reg-resident dist update + thread argmax
// -> 64-lane u64 butterfly -> LDS handoff + ONE barrier -> wave0 lanes
// 0..1 store 32B slot {key|coords} as two self-validating 16B quads ->
// ALL waves poll (lane L owns quad L) -> butterfly -> coords via shfl.
// Key = dist_bits<<32 | step<<17 | (0x1FFFF - idx): u64 max ==
// (dist desc, idx asc) == jnp.argmax first-index tiebreak. Exact fp32
// (contract off, __fmul_rn/__fadd_rn) matches the numpy reference.
// Ring safety (RING=4): store(s+4) needs poll(s+3) passed by all =>
// every tag-s read completed first. Own-slot polling proves own-store
// visibility despite fire-and-forget. Zero/0xAA slots never tag-match.

#define NB    32
#define TPB   256
#define PPT   16      // 32*256*16 = 131072
#define NPB   131072
#define MSAMP 4096
#define RING  4
#define GRID  256
#define KTO   8192    // poll iterations before scope downgrade

typedef unsigned long long u64;
typedef unsigned int u32;
typedef __attribute__((ext_vector_type(4))) u32 u32x4;

__device__ __forceinline__ u32x4 ld16_sys(const u32* p) {
  u32x4 r;
  asm volatile("global_load_dwordx4 %0, %1, off sc0 sc1\n\ts_waitcnt vmcnt(0)"
               : "=v"(r) : "v"(p) : "memory");
  return r;
}
__device__ __forceinline__ u32x4 ld16_l2(const u32* p) {
  u32x4 r;
  asm volatile("global_load_dwordx4 %0, %1, off sc0\n\ts_waitcnt vmcnt(0)"
               : "=v"(r) : "v"(p) : "memory");
  return r;
}
__device__ __forceinline__ void st16_sys(u32* p, u32x4 v) {  // fire-and-forget
  asm volatile("global_store_dwordx4 %0, %1, off sc0 sc1"
               :: "v"(p), "v"(v) : "memory");
}
__device__ __forceinline__ void st16_l2(u32* p, u32x4 v) {
  asm volatile("global_store_dwordx4 %0, %1, off sc0"
               :: "v"(p), "v"(v) : "memory");
}

__global__ __launch_bounds__(TPB, 1)
void fps_kernel(const float4* __restrict__ pts, float* __restrict__ out,
                u32* __restrict__ slots)
{
#pragma clang fp contract(off)
  const int bid = blockIdx.x;
  const int sub = bid & 7;
  if (sub >= 2) return;                      // non-worker: exit instantly
  const int batch = sub;
  const int blk   = bid >> 3;                // 0..31

  const int tid  = threadIdx.x;
  const int lane = tid & 63;
  const int wv   = tid >> 6;
  const float4* bpts = pts + (size_t)batch * NPB;
  u32* bslots = slots + (size_t)batch * (RING * NB * 8);  // 8 u32 per slot

  __shared__ u64   s_key[4];
  __shared__ float s_cx[4], s_cy[4], s_cz[4];

  u32 myxcd;
  asm("s_getreg_b32 %0, hwreg(20, 0, 32)" : "=s"(myxcd));  // HW_REG_XCC_ID
  myxcd &= 7u;

  const int base = blk * (TPB * PPT);
  float px[PPT], py[PPT], pz[PPT], dist[PPT];
#pragma unroll
  for (int k = 0; k < PPT; ++k) {
    float4 p = bpts[base + k * TPB + tid];   // row = (b, x, y, z)
    px[k] = p.y; py[k] = p.z; pz[k] = p.w;
    dist[k] = __builtin_inff();              // min(inf, d) == d bit-exactly
  }

  float4 seed = bpts[0];
  float sx = seed.y, sy = seed.z, sz = seed.w;
  if (blk == 0 && wv == 0 && lane == 0) {
    float4 o; o.x = (float)batch; o.y = sx; o.z = sy; o.w = sz;
    *(float4*)(out + (size_t)batch * MSAMP * 4) = o;
  }

  bool l2m = false, sticky = false;          // start at system scope
  u32x4 h0 = (u32x4)(0u), h1 = (u32x4)(0u),  // my ring history (storer lanes)
        h2 = (u32x4)(0u), h3 = (u32x4)(0u);

  for (int s = 1; s < MSAMP; ++s) {
    // ---- fused dist update + per-thread argmax, coords tracked ----
    float bestd = -1.0f, bx = 0.f, by = 0.f, bz = 0.f; int besti = 0;
#pragma unroll
    for (int k = 0; k < PPT; ++k) {
      float dx = px[k] - sx, dy = py[k] - sy, dz = pz[k] - sz;
      float d2 = __fadd_rn(__fadd_rn(__fmul_rn(dx, dx), __fmul_rn(dy, dy)),
                           __fmul_rn(dz, dz));
      float nd = fminf(dist[k], d2);
      dist[k] = nd;
      if (nd > bestd) {                      // strict '>': first-index tiebreak
        bestd = nd; besti = base + k * TPB + tid;
        bx = px[k]; by = py[k]; bz = pz[k];
      }
    }

    u64 pv0 = ((u64)__float_as_uint(bestd) << 32) | ((u64)s << 17) |
              (u64)(0x1FFFF - besti);
    u64 pv = pv0;
#pragma unroll
    for (int m = 32; m >= 1; m >>= 1) {
      u64 o = __shfl_xor(pv, m, 64);
      if (o > pv) pv = o;
    }
    int wl = __ffsll(__ballot(pv0 == pv)) - 1;   // keys unique (idx embedded)
    float wx = __shfl(bx, wl, 64), wy = __shfl(by, wl, 64),
          wz = __shfl(bz, wl, 64);
    if (lane == 0) { s_key[wv] = pv; s_cx[wv] = wx; s_cy[wv] = wy; s_cz[wv] = wz; }
    __syncthreads();                         // one barrier per step

    u32* ring = bslots + (size_t)(s & (RING - 1)) * (NB * 8);
    if (wv == 0 && lane < 2) {
      u64 k0 = s_key[0], k1 = s_key[1], k2 = s_key[2], k3 = s_key[3];
      int bi = 0; u64 bk = k0;
      if (k1 > bk) { bk = k1; bi = 1; }
      if (k2 > bk) { bk = k2; bi = 2; }
      if (k3 > bk) { bk = k3; bi = 3; }
      u32x4 q;
      if (lane == 0) {                       // quad0: key(lo=tag|idx,hi=dist)+x,y
        q.x = (u32)(bk & 0xFFFFFFFFull); q.y = (u32)(bk >> 32);
        q.z = __float_as_uint(s_cx[bi]);  q.w = __float_as_uint(s_cy[bi]);
      } else {                               // quad1: tag + z + xcd + check
        q.x = (u32)s; q.y = __float_as_uint(s_cz[bi]);
        q.z = myxcd;  q.w = myxcd ^ 0xA5u;
      }
      switch (s & 3) {                       // keep ring history in registers
        case 0: h0 = q; break; case 1: h1 = q; break;
        case 2: h2 = q; break; default: h3 = q; break;
      }
      u32* sp = ring + blk * 8 + lane * 4;
      if (l2m) st16_l2(sp, q); else st16_sys(sp, q);   // fire-and-forget
    }

    // ---- bounded poll: lane L owns quad L (slot L>>1, half L&1) ----
    const u32* pp = ring + lane * 4;
    u32x4 q;
    int iters = 0;
    for (;;) {
      q = l2m ? ld16_l2(pp) : ld16_sys(pp);
      bool ok = ((lane & 1) == 0) ? ((q.x >> 17) == (u32)s) : (q.x == (u32)s);
      if (__ballot(ok) == ~0ull) break;
      if (++iters >= KTO) {                  // timeout: sticky downgrade
        iters = 0; sticky = true; l2m = false;
        if (wv == 0 && lane < 2) {           // republish my whole ring at SYS
          u32* rb = bslots + blk * 8 + lane * 4;
          st16_sys(rb + 0 * (NB * 8), h0);
          st16_sys(rb + 1 * (NB * 8), h1);
          st16_sys(rb + 2 * (NB * 8), h2);
          st16_sys(rb + 3 * (NB * 8), h3);
        }
      }
      if (!l2m) __builtin_amdgcn_s_sleep(1);
    }

    // ---- one-time scope decision after step-1 round (batch-uniform) ----
    if (s == 1) {
      u32 ref = (u32)__shfl((int)q.z, 1, 64);    // lane1 = slot0 quad1 xcd
      bool okl = ((lane & 1) == 0) ||
                 (q.z == ref && q.w == (q.z ^ 0xA5u));
      l2m = (__ballot(okl) == ~0ull) && !sticky; // all 32 ids uniform
    }

    // ---- cross-block argmax + register-resident coord extraction ----
    u64 key = ((lane & 1) == 0) ? (((u64)q.y << 32) | (u64)q.x) : 0ull;
    u64 w = key;
#pragma unroll
    for (int m = 32; m >= 1; m >>= 1) {
      u64 o = __shfl_xor(w, m, 64);
      if (o > w) w = o;
    }
    int wl2 = __ffsll(__ballot(key == w && ((lane & 1) == 0))) - 1;
    sx = __shfl(__uint_as_float(q.z), wl2, 64);      // x from quad0 lane
    sy = __shfl(__uint_as_float(q.w), wl2, 64);      // y from quad0 lane
    sz = __shfl(__uint_as_float(q.y), wl2 + 1, 64);  // z from quad1 lane

    if (blk == 0 && wv == 0 && lane == 0) {
      float4 o; o.x = (float)batch; o.y = sx; o.z = sy; o.w = sz;
      *(float4*)(out + (size_t)(batch * MSAMP + s) * 4) = o;
    }
  }
}

extern "C" void kernel_launch(void* const* d_in, const int* in_sizes, int n_in,
                              void* d_out, int out_size, void* d_ws, size_t ws_size,
                              hipStream_t stream) {
  const float4* pts = (const float4*)d_in[0];
  float* out = (float*)d_out;
  u32* slots = (u32*)d_ws;

  // Zero both batches' slot rings (8 KB): poisoned tags never validate.
  hipMemsetAsync(d_ws, 0, (size_t)2 * RING * NB * 32, stream);

  dim3 grid(GRID), block(TPB);
  hipLaunchKernelGGL(fps_kernel, grid, block, 0, stream, pts, out, slots);
}